// Round 1
// baseline (1859.587 us; speedup 1.0000x reference)
//
#include <hip/hip_runtime.h>

#define THREADS 256
#define MU_C  0.1f
#define EPS_C 0.01f

// ---------- fast math helpers ----------
__device__ __forceinline__ float fast_exp2(float x) {
#if defined(__has_builtin)
#if __has_builtin(__builtin_amdgcn_exp2f)
    return __builtin_amdgcn_exp2f(x);
#else
    return exp2f(x);
#endif
#else
    return exp2f(x);
#endif
}

__device__ __forceinline__ float fast_rcp(float x) {
#if defined(__has_builtin)
#if __has_builtin(__builtin_amdgcn_rcpf)
    return __builtin_amdgcn_rcpf(x);
#else
    return 1.0f / x;
#endif
#else
    return 1.0f / x;
#endif
}

// tanh(x) = 1 - 2/(exp(2x)+1);  2*log2(e) = 2.885390081777927
__device__ __forceinline__ float fast_tanh(float x) {
    float e = fast_exp2(x * 2.88539008177792681472f);
    return 1.0f - 2.0f * fast_rcp(e + 1.0f);
}

// 64-length dot, 4 independent accumulators (avoid serial FMA chain)
__device__ __forceinline__ float dot64(const float* __restrict__ w, const float (&h)[64]) {
    float a0 = 0.f, a1 = 0.f, a2 = 0.f, a3 = 0.f;
#pragma unroll
    for (int k = 0; k < 64; k += 4) {
        a0 += w[k + 0] * h[k + 0];
        a1 += w[k + 1] * h[k + 1];
        a2 += w[k + 2] * h[k + 2];
        a3 += w[k + 3] * h[k + 3];
    }
    return (a0 + a1) + (a2 + a3);
}

__device__ __forceinline__ float dot16(const float* __restrict__ w, const float (&h)[16]) {
    float a0 = 0.f, a1 = 0.f, a2 = 0.f, a3 = 0.f;
#pragma unroll
    for (int k = 0; k < 16; k += 4) {
        a0 += w[k + 0] * h[k + 0];
        a1 += w[k + 1] * h[k + 1];
        a2 += w[k + 2] * h[k + 2];
        a3 += w[k + 3] * h[k + 3];
    }
    return (a0 + a1) + (a2 + a3);
}

__global__ __launch_bounds__(THREADS, 2)
void ph_shnd_kernel(const float* __restrict__ zg, const float* __restrict__ ug,
                    const float* __restrict__ Wh1, const float* __restrict__ bh1,
                    const float* __restrict__ Wh2,
                    const float* __restrict__ W1jr, const float* __restrict__ b1jr,
                    const float* __restrict__ W2jr, const float* __restrict__ b2jr,
                    const float* __restrict__ W3jr, const float* __restrict__ b3jr,
                    const float* __restrict__ W1b, const float* __restrict__ b1b,
                    const float* __restrict__ W2b, const float* __restrict__ b2b,
                    const float* __restrict__ W3b, const float* __restrict__ b3b,
                    float* __restrict__ out, int B)
{
    // Per-thread LDS slices; odd word strides -> conflict-free when the
    // runtime index is wave-uniform (it always is: loop counters).
    __shared__ float gqL[THREADS * 17];   // gH copy (runtime-j reads)
    __shared__ float qL [THREADS * 17];   // shared q / rfv accumulator
    __shared__ float uL [THREADS * 9];    // u (runtime-m reads)
    __shared__ float yL [THREADS * 9];    // y accumulator

    const int tid = threadIdx.x;
    const int idx = blockIdx.x * THREADS + tid;
    if (idx >= B) return;

    float* __restrict__ gq  = gqL + tid * 17;
    float* __restrict__ qsh = qL  + tid * 17;
    float* __restrict__ uT  = uL  + tid * 9;
    float* __restrict__ yT  = yL  + tid * 9;

    // ---- load z, u ----
    float cz[16];
    {
        const float4* zp = reinterpret_cast<const float4*>(zg + (size_t)idx * 16);
        float4 a0 = zp[0], a1 = zp[1], a2 = zp[2], a3 = zp[3];
        cz[0]=a0.x; cz[1]=a0.y; cz[2]=a0.z; cz[3]=a0.w;
        cz[4]=a1.x; cz[5]=a1.y; cz[6]=a1.z; cz[7]=a1.w;
        cz[8]=a2.x; cz[9]=a2.y; cz[10]=a2.z; cz[11]=a2.w;
        cz[12]=a3.x; cz[13]=a3.y; cz[14]=a3.z; cz[15]=a3.w;
    }
    {
        const float4* up = reinterpret_cast<const float4*>(ug + (size_t)idx * 8);
        float4 u0 = up[0], u1 = up[1];
        uT[0]=u0.x; uT[1]=u0.y; uT[2]=u0.z; uT[3]=u0.w;
        uT[4]=u1.x; uT[5]=u1.y; uT[6]=u1.z; uT[7]=u1.w;
    }

    float dzA[16];   // dz from pass 0
    float dzB[16];   // dz from pass 1

#pragma unroll 1
    for (int pass = 0; pass < 2; ++pass) {
        // ================= Hamiltonian gradient =================
        // f = mu*z + Wh2 @ tanh(Wh1 z + bh1)
        float fv[16];
#pragma unroll
        for (int i = 0; i < 16; ++i) fv[i] = MU_C * cz[i];
#pragma unroll 1
        for (int k = 0; k < 128; ++k) {
            float a = bh1[k] + dot16(Wh1 + k * 16, cz);
            float t = fast_tanh(a);
#pragma unroll
            for (int i = 0; i < 16; ++i) fv[i] += Wh2[i * 128 + k] * t;
        }
        // gH = mu*f + Wh1^T [ (1-t^2) * (Wh2^T f) ]   (recompute t per k)
        float gH[16];
#pragma unroll
        for (int i = 0; i < 16; ++i) gH[i] = MU_C * fv[i];
#pragma unroll 1
        for (int k = 0; k < 128; ++k) {
            float a = bh1[k] + dot16(Wh1 + k * 16, cz);
            float t = fast_tanh(a);
            float v0 = 0.f, v1 = 0.f, v2 = 0.f, v3 = 0.f;
#pragma unroll
            for (int i = 0; i < 16; i += 4) {
                v0 += Wh2[(i + 0) * 128 + k] * fv[i + 0];
                v1 += Wh2[(i + 1) * 128 + k] * fv[i + 1];
                v2 += Wh2[(i + 2) * 128 + k] * fv[i + 2];
                v3 += Wh2[(i + 3) * 128 + k] * fv[i + 3];
            }
            float s = (1.0f - t * t) * ((v0 + v1) + (v2 + v3));
#pragma unroll
            for (int j = 0; j < 16; ++j) gH[j] += s * Wh1[k * 16 + j];
        }
        // stash gH in LDS for runtime-index reads
#pragma unroll
        for (int i = 0; i < 16; ++i) gq[i] = gH[i];

        // ================= JR net hiddens =================
        float h1[64];
#pragma unroll
        for (int o = 0; o < 64; ++o) {
            h1[o] = fast_tanh(b1jr[o] + dot16(W1jr + o * 16, cz));
        }
        float h2[64];
#pragma unroll
        for (int o = 0; o < 64; ++o) {
            h2[o] = fast_tanh(b2jr[o] + dot64(W2jr + o * 64, h1));
        }

        // ================= JR layer-3 contractions =================
        // Jm part: p_i = sum_j Jm[i,j] gH_j ; q_j = sum_i Jm[i,j] gH_i
        float dzp[16];
#pragma unroll
        for (int j = 0; j < 16; ++j) qsh[j] = 0.f;
#pragma unroll
        for (int i = 0; i < 16; ++i) {
            float pi = 0.f;
#pragma unroll 1
            for (int j = 0; j < 16; ++j) {
                const int c = i * 16 + j;
                float val = b3jr[c] + dot64(W3jr + c * 64, h2);
                pi += val * gq[j];            // p_i += Jm[i,j]*gH[j]
                qsh[j] += val * gH[i];        // q_j += Jm[i,j]*gH[i]
            }
            dzp[i] = pi;
        }
#pragma unroll
        for (int i = 0; i < 16; ++i) dzp[i] -= qsh[i];   // p - q

        // Rf part: rfv_j = sum_i Rf[i,j] gH_i  (reuse qsh as rfv)
#pragma unroll
        for (int j = 0; j < 16; ++j) qsh[j] = 0.f;
#pragma unroll
        for (int i = 0; i < 16; ++i) {
#pragma unroll 1
            for (int j = 0; j < 16; ++j) {
                const int c = 256 + i * 16 + j;
                float val = b3jr[c] + dot64(W3jr + c * 64, h2);
                qsh[j] += val * gH[i];
            }
        }
        // racc_i = sum_j Rf[i,j] rfv_j   (recompute Rf row values)
        float racc[16];
#pragma unroll
        for (int i = 0; i < 16; ++i) {
            float r = 0.f;
#pragma unroll 1
            for (int j = 0; j < 16; ++j) {
                const int c = 256 + i * 16 + j;
                float val = b3jr[c] + dot64(W3jr + c * 64, h2);
                r += val * qsh[j];
            }
            racc[i] = r;
        }

        // ================= B net =================
        float g1[64];
#pragma unroll
        for (int o = 0; o < 64; ++o) {
            g1[o] = fast_tanh(b1b[o] + dot16(W1b + o * 16, cz));
        }
        float g2[64];
#pragma unroll
        for (int o = 0; o < 64; ++o) {
            g2[o] = fast_tanh(b2b[o] + dot64(W2b + o * 64, g1));
        }

        // Bu_d = sum_m Bmat[d,m] u_m ; y_m = sum_d Bmat[d,m] gH_d
#pragma unroll
        for (int m = 0; m < 8; ++m) yT[m] = 0.f;    // pass 1 overwrites pass 0
        float Bu[16];
#pragma unroll
        for (int d = 0; d < 16; ++d) {
            float bu = 0.f;
#pragma unroll 1
            for (int m = 0; m < 8; ++m) {
                const int c = d * 8 + m;
                float val = b3b[c] + dot64(W3b + c * 64, g2);
                bu += val * uT[m];
                yT[m] += val * gH[d];
            }
            Bu[d] = bu;
        }

        // ================= assemble dz =================
        if (pass == 0) {
#pragma unroll
            for (int i = 0; i < 16; ++i) {
                float d = dzp[i] - racc[i] + Bu[i] - EPS_C * gH[i];
                dzA[i] = d;
                cz[i] += d;                    // z1 = z + dz1 (DT = 1)
            }
        } else {
#pragma unroll
            for (int i = 0; i < 16; ++i) {
                dzB[i] = dzp[i] - racc[i] + Bu[i] - EPS_C * gH[i];
            }
        }
    }

    // ---- epilogue: z_next = z + 0.5*(dz1+dz2), y_pred from pass 1 ----
    {
        const float4* zp = reinterpret_cast<const float4*>(zg + (size_t)idx * 16);
        float4 a0 = zp[0], a1 = zp[1], a2 = zp[2], a3 = zp[3];
        float zo[16];
        zo[0]=a0.x; zo[1]=a0.y; zo[2]=a0.z; zo[3]=a0.w;
        zo[4]=a1.x; zo[5]=a1.y; zo[6]=a1.z; zo[7]=a1.w;
        zo[8]=a2.x; zo[9]=a2.y; zo[10]=a2.z; zo[11]=a2.w;
        zo[12]=a3.x; zo[13]=a3.y; zo[14]=a3.z; zo[15]=a3.w;

        float4* op = reinterpret_cast<float4*>(out + (size_t)idx * 16);
#pragma unroll
        for (int q4 = 0; q4 < 4; ++q4) {
            float4 o;
            o.x = zo[q4*4+0] + 0.5f * (dzA[q4*4+0] + dzB[q4*4+0]);
            o.y = zo[q4*4+1] + 0.5f * (dzA[q4*4+1] + dzB[q4*4+1]);
            o.z = zo[q4*4+2] + 0.5f * (dzA[q4*4+2] + dzB[q4*4+2]);
            o.w = zo[q4*4+3] + 0.5f * (dzA[q4*4+3] + dzB[q4*4+3]);
            op[q4] = o;
        }

        float4* yp = reinterpret_cast<float4*>(out + (size_t)B * 16 + (size_t)idx * 8);
        float4 y0, y1;
        y0.x = yT[0]; y0.y = yT[1]; y0.z = yT[2]; y0.w = yT[3];
        y1.x = yT[4]; y1.y = yT[5]; y1.z = yT[6]; y1.w = yT[7];
        yp[0] = y0;
        yp[1] = y1;
    }
}

extern "C" void kernel_launch(void* const* d_in, const int* in_sizes, int n_in,
                              void* d_out, int out_size, void* d_ws, size_t ws_size,
                              hipStream_t stream) {
    const float* zg   = (const float*)d_in[0];
    const float* ug   = (const float*)d_in[1];
    const float* Wh1  = (const float*)d_in[2];
    const float* bh1  = (const float*)d_in[3];
    const float* Wh2  = (const float*)d_in[4];
    const float* W1jr = (const float*)d_in[5];
    const float* b1jr = (const float*)d_in[6];
    const float* W2jr = (const float*)d_in[7];
    const float* b2jr = (const float*)d_in[8];
    const float* W3jr = (const float*)d_in[9];
    const float* b3jr = (const float*)d_in[10];
    const float* W1b  = (const float*)d_in[11];
    const float* b1b  = (const float*)d_in[12];
    const float* W2b  = (const float*)d_in[13];
    const float* b2b  = (const float*)d_in[14];
    const float* W3b  = (const float*)d_in[15];
    const float* b3b  = (const float*)d_in[16];

    const int B = in_sizes[0] / 16;
    const int grid = (B + THREADS - 1) / THREADS;

    hipLaunchKernelGGL(ph_shnd_kernel, dim3(grid), dim3(THREADS), 0, stream,
                       zg, ug, Wh1, bh1, Wh2,
                       W1jr, b1jr, W2jr, b2jr, W3jr, b3jr,
                       W1b, b1b, W2b, b2b, W3b, b3b,
                       (float*)d_out, B);
}